// Round 5
// baseline (12562.977 us; speedup 1.0000x reference)
//
#include <hip/hip_runtime.h>
#include <math.h>

// ---------------------------------------------------------------------------
// RITS forward, round 9: r8 (phase-minimized, 7 barriers/step) with the
// phase-C readback BUG FIXED: each partner payload is 128 u32 (32 kp-pairs x
// 4 rows); r8 read only 32. Fix: 6 waves (tid<384), lane0-per-wave spins on
// the partner flag (acquire, AGENT), then the whole wave pulls its 64-word
// half-payload via relaxed AGENT loads (L1-bypassing) - no extra barrier.
// Everything else identical to r8. B=256, L=256, D=128, H=256.
// ---------------------------------------------------------------------------

namespace {
constexpr int Bn = 256, Ln = 256, Dn = 128, Hn = 256;
constexpr long LD = (long)Ln * Dn;  // 32768

// ws byte offsets
constexpr int OFF_LOSS  = 0;
constexpr int OFF_DEN   = 256;      // 256 f32
constexpr int OFF_BIASG = 2048;     // 1024 f32 [jj][q]
constexpr int OFF_WG    = 8192;     // 262144 dw: [kp<128][jj<256][8]
constexpr int OFF_HISTP = 1056768;  // 16384 dw [kp<128][d<128]
constexpr int OFF_TDHP  = 1122304;  // 16384 dw [kp<64][h<256]
constexpr int OFF_WFP   = 1187840;  // 8192 dw  [kp<64][d<128] (diag=0)
constexpr int OFF_WCP   = 1220608;  // 16384 dw [kp<128][d<128]
constexpr int OFF_EXCH  = 1286144;  // 256 blk * 2 parity * 1024 B
constexpr int OFF_FLAG  = 1810432;  // 256 flags * 64 B
}  // namespace

typedef _Float16 h2f __attribute__((ext_vector_type(2)));
typedef unsigned int uint32;

__device__ __forceinline__ float fdot2(uint32 a, uint32 b, float c) {
  return __builtin_amdgcn_fdot2(__builtin_bit_cast(h2f, a),
                                __builtin_bit_cast(h2f, b), c, false);
}
__device__ __forceinline__ uint32 packf16(float a, float b) {
  h2f p; p[0] = (_Float16)a; p[1] = (_Float16)b;
  return __builtin_bit_cast(uint32, p);
}

// ======================= K1: repack + biases + denom ========================
__global__ void rits_prep(const float* __restrict__ td_h_W,
                          const float* __restrict__ hist_W,
                          const float* __restrict__ feat_W,
                          const float* __restrict__ wc_W,
                          const float* __restrict__ W_ih,
                          const float* __restrict__ W_hh,
                          const float* __restrict__ b_ih,
                          const float* __restrict__ b_hh,
                          const float* __restrict__ evalm,
                          char* __restrict__ wsb) {
  const int blk = blockIdx.x, tid = threadIdx.x;
  if (blk < 1248) {
    int idx = blk * 256 + tid;
    if (idx < 262144) {  // wg
      int kp = idx >> 11, rem = idx & 2047, jj = rem >> 3, s8 = rem & 7;
      const float* src = (s8 < 4) ? W_ih : W_hh;
      int q = s8 & 3;
      const float* row = src + (size_t)(q * 256 + jj) * 256 + 2 * kp;
      ((uint32*)(wsb + OFF_WG))[idx] = packf16(row[0], row[1]);
    } else if (idx < 278528) {  // histP
      int i2 = idx - 262144, kp = i2 >> 7, d = i2 & 127;
      ((uint32*)(wsb + OFF_HISTP))[i2] =
          packf16(hist_W[d * 256 + 2 * kp], hist_W[d * 256 + 2 * kp + 1]);
    } else if (idx < 294912) {  // tdhP [kp<64][h<256]
      int i2 = idx - 278528, kp = i2 >> 8, h = i2 & 255;
      ((uint32*)(wsb + OFF_TDHP))[i2] =
          packf16(td_h_W[h * 128 + 2 * kp], td_h_W[h * 128 + 2 * kp + 1]);
    } else if (idx < 303104) {  // wfP: [kp<64][d<128], diag=0
      int i2 = idx - 294912, kp = i2 >> 7, d = i2 & 127;
      float a = (2 * kp == d) ? 0.f : feat_W[d * 128 + 2 * kp];
      float b = (2 * kp + 1 == d) ? 0.f : feat_W[d * 128 + 2 * kp + 1];
      ((uint32*)(wsb + OFF_WFP))[i2] = packf16(a, b);
    } else if (idx < 319488) {  // wcP [kp<128][d<128]
      int i2 = idx - 303104, kp = i2 >> 7, d = i2 & 127;
      ((uint32*)(wsb + OFF_WCP))[i2] =
          packf16(wc_W[d * 256 + 2 * kp], wc_W[d * 256 + 2 * kp + 1]);
    }
  } else if (blk < 1252) {  // biasg
    int i = (blk - 1248) * 256 + tid;
    int jj = i >> 2, q = i & 3;
    ((float*)(wsb + OFF_BIASG))[jj * 4 + q] =
        b_ih[q * 256 + jj] + b_hh[q * 256 + jj];
    if (blk == 1248 && tid == 0) *((float*)(wsb + OFF_LOSS)) = 0.f;
  } else if (blk < 1508) {  // denom per t
    int t = blk - 1252;
    __shared__ float red[256];
    int d = tid & 127, g = tid >> 7;
    float s = 0.f;
    for (int b = g; b < 256; b += 2) s += evalm[(size_t)b * LD + t * 128 + d];
    red[tid] = s;
    __syncthreads();
    for (int o = 128; o > 0; o >>= 1) {
      if (tid < o) red[tid] += red[tid + o];
      __syncthreads();
    }
    if (tid == 0) ((float*)(wsb + OFF_DEN))[t] = red[0] + 1e-5f;
  } else {  // blk == 1508: zero exchange flags
    for (int i = tid; i < 4096; i += 256) ((uint32*)(wsb + OFF_FLAG))[i] = 0u;
  }
}

// ========================== K2: recurrent blocks ============================
__global__ __launch_bounds__(1024, 4) void rits_rec(
    const float* __restrict__ values, const float* __restrict__ masks,
    const float* __restrict__ deltas,
    const float* __restrict__ td_h_b, const float* __restrict__ td_x_w,
    const float* __restrict__ td_x_b, const float* __restrict__ hist_b,
    const float* __restrict__ feat_b, const float* __restrict__ wc_b,
    char* __restrict__ wsb, float* __restrict__ outp) {
  __shared__ uint32 histL[16384];                // 64 KB [kp<128][d<128]
  __shared__ uint32 wfL[8192];                   // 32 KB [kp<64][d<128]
  __shared__ __align__(16) float scratch[9216];  // 36 KB partials
  __shared__ __align__(16) uint32 hdP[512];      // full hd pairs [kp][r]
  __shared__ __align__(16) uint32 cmP[512];      // [c_c|m] pairs [kp][r]
  __shared__ __align__(16) uint32 xcP[256];      // x_c pairs [kp][r]
  __shared__ __align__(16) uint32 drP[256];      // delta(t+1) pairs [kp][r]
  __shared__ __align__(16) uint32 gxmP[512];     // [gamma_x|m] pairs [kp][r]
  __shared__ float gbufF[256];                   // gamma_h own qtr [r][hl]
  __shared__ float hf[4][64], cst[4][64];        // own h-quarter state
  __shared__ float txw_s[128], txb_s[128], hb_s[128], fb_s[128], wcb_s[128];
  __shared__ float tdhb_s[64], bg_s[256];        // bg as [q][jj]

  const int tid = threadIdx.x;
  const int bid = blockIdx.x;
  const int sh = bid >> 6;    // owned h/jj quarter 0..3
  const int grp = bid & 63;   // group: rows 4*grp..4*grp+3
  const size_t b0 = (size_t)grp * 4;
  const uint32* wg = (const uint32*)(wsb + OFF_WG);
  const uint32* tdhG = (const uint32*)(wsb + OFF_TDHP);
  const uint32* wcG = (const uint32*)(wsb + OFF_WCP);
  char* exch = wsb + OFF_EXCH;
  unsigned int* flg = (unsigned int*)(wsb + OFF_FLAG);

  // role indices
  const int dA = tid & 127, rA = tid >> 7;            // (d,r) roles, tid<512
  const int dD = tid & 127, kqD = tid >> 7;           // D: (d, kq<8)
  const int jjH = tid & 63, qhH = (tid >> 6) & 1, kqH = tid >> 7;  // H gates
  const int jg = sh * 64 + jjH;
  const int jjG = tid & 63, rG = (tid >> 6) & 3, kslG = tid >> 8;  // H gamma

  // -------- LDS preloads --------
  {
    const uint4* hG = (const uint4*)(wsb + OFF_HISTP);
#pragma unroll
    for (int k = 0; k < 4; ++k) ((uint4*)histL)[k * 1024 + tid] = hG[k * 1024 + tid];
    const uint4* fG = (const uint4*)(wsb + OFF_WFP);
#pragma unroll
    for (int k = 0; k < 2; ++k) ((uint4*)wfL)[k * 1024 + tid] = fG[k * 1024 + tid];
  }
  if (tid < 128) txw_s[tid] = td_x_w[tid];
  else if (tid < 256) txb_s[tid - 128] = td_x_b[tid - 128];
  else if (tid < 384) hb_s[tid - 256] = hist_b[tid - 256];
  else if (tid < 512) fb_s[tid - 384] = feat_b[tid - 384];
  else if (tid < 640) wcb_s[tid - 512] = wc_b[tid - 512];
  else if (tid < 704) tdhb_s[tid - 640] = td_h_b[sh * 64 + (tid - 640)];
  else if (tid < 960) {
    int i = tid - 704;
    bg_s[i] = ((const float*)(wsb + OFF_BIASG))[(sh * 64 + (i & 63)) * 4 + (i >> 6)];
  }
  if (tid < 256) ((float*)hf)[tid] = 0.f;
  else if (tid < 512) ((float*)cst)[tid - 256] = 0.f;

  // -------- register weight preloads --------
  uint2 wv_[16], wh_[16];  // gate weights: 16 kp x 2 q = 64 VGPR
#pragma unroll
  for (int i = 0; i < 16; ++i) {
    const uint32* p = wg + ((size_t)((kqH * 16 + i) * 256 + jg)) * 8 + 2 * qhH;
    wv_[i] = *(const uint2*)p;
    wh_[i] = *(const uint2*)(p + 4);
  }
  uint32 twr[16];          // tdh gamma weights: 16 VGPR
#pragma unroll
  for (int i = 0; i < 16; ++i)
    twr[i] = tdhG[(kslG * 16 + i) * 256 + sh * 64 + jjG];
  __syncthreads();

  // -------- prime: inputs t0/t1, gxm(0), drP(0) --------
  float xv = 0.f, mv = 0.f, xvn = 0.f, mvn = 0.f, dvn = 0.f;
  if (tid < 512) {
    size_t g0 = b0 * LD + (size_t)rA * LD + dA;
    xv = values[g0]; mv = masks[g0];
    float dv0 = deltas[g0];
    float gx = __expf(-fmaxf(fmaf(dv0, txw_s[dA], txb_s[dA]), 0.f));
    float gxo = __shfl_down(gx, 1);
    float dvo = __shfl_down(dv0, 1);
    float mvo = __shfl_down(mv, 1);
    if (!(dA & 1)) {
      gxmP[(dA >> 1) * 4 + rA] = packf16(gx, gxo);
      gxmP[(64 + (dA >> 1)) * 4 + rA] = packf16(mv, mvo);
      drP[(dA >> 1) * 4 + rA] = packf16(dv0, dvo);
    }
    size_t g1 = g0 + 128;
    xvn = values[g1]; mvn = masks[g1]; dvn = deltas[g1];
  }
  __syncthreads();
  {  // gamma(0) partials
    float gp = 0.f;
#pragma unroll
    for (int i = 0; i < 16; ++i)
      gp = fdot2(drP[(kslG * 16 + i) * 4 + rG], twr[i], gp);
    scratch[8192 + (kslG * 4 + rG) * 64 + jjG] = gp;
  }
  __syncthreads();
  if (tid < 256) {  // gamma(0) finalize
    int jj = tid & 63, r = tid >> 6;
    float s = tdhb_s[jj];
#pragma unroll
    for (int ks = 0; ks < 4; ++ks) s += scratch[8192 + (ks * 4 + r) * 64 + jj];
    gbufF[r * 64 + jj] = __expf(-fmaxf(s, 0.f));
  }
  __syncthreads();

  float xh = 0.f, av = 0.f;
  for (int t = 0; t < Ln; ++t) {
    const size_t base = b0 * LD + (size_t)t * 128;
    uint32* mypU = (uint32*)(exch + (size_t)(bid * 2 + (t & 1)) * 1024);

    // ---- B: hd own quarter + post  |  alpha partials (streamed wc) ----
    if (tid < 128) {
      int kpl = tid & 31, r = tid >> 5;
      float g0 = gbufF[r * 64 + 2 * kpl], g1 = gbufF[r * 64 + 2 * kpl + 1];
      uint32 pv = packf16(hf[r][2 * kpl] * g0, hf[r][2 * kpl + 1] * g1);
      hdP[(sh * 32 + kpl) * 4 + r] = pv;
      __hip_atomic_store(mypU + kpl * 4 + r, pv, __ATOMIC_RELAXED,
                         __HIP_MEMORY_SCOPE_AGENT);
    } else if (tid >= 512) {
      int i0 = tid - 512, d = i0 & 127, kq = i0 >> 7;  // kq<4
      float a0 = 0.f, a1 = 0.f, a2 = 0.f, a3 = 0.f;
#pragma unroll 8
      for (int i2 = 0; i2 < 32; ++i2) {
        int kp = kq * 32 + i2;
        uint32 w = wcG[kp * 128 + d];
        uint4 g4 = *(const uint4*)&gxmP[kp * 4];
        a0 = fdot2(g4.x, w, a0); a1 = fdot2(g4.y, w, a1);
        a2 = fdot2(g4.z, w, a2); a3 = fdot2(g4.w, w, a3);
      }
      scratch[4096 + (kq * 4 + 0) * 128 + d] = a0;
      scratch[4096 + (kq * 4 + 1) * 128 + d] = a1;
      scratch[4096 + (kq * 4 + 2) * 128 + d] = a2;
      scratch[4096 + (kq * 4 + 3) * 128 + d] = a3;
    }
    __syncthreads();  // drains vmcnt: hd posts visible

    // ---- C: release flag; lane0-per-wave spin; pull FULL partner payloads --
    if (tid == 0)
      __hip_atomic_store(flg + bid * 16, (unsigned)(t + 1), __ATOMIC_RELEASE,
                         __HIP_MEMORY_SCOPE_AGENT);
    if (tid < 384) {  // 6 waves; wave w covers half of partner (w>>1)'s 128 u32
      int w = tid >> 6, lane = tid & 63;
      int p = w >> 1;
      int ps = p + (p >= sh ? 1 : 0);
      unsigned* pfp = flg + (ps * 64 + grp) * 16;
      if (lane == 0) {
        unsigned guard = 0;
        while (__hip_atomic_load(pfp, __ATOMIC_ACQUIRE,
                                 __HIP_MEMORY_SCOPE_AGENT) < (unsigned)(t + 1)) {
          if (++guard > (1u << 22)) break;  // bounded: avoid hard hang
        }
      }
      // wave reconverges after lane0's spin; relaxed AGENT loads bypass L1
      int j = ((w & 1) << 6) + lane;
      const uint32* pq =
          (const uint32*)(exch + (size_t)((ps * 64 + grp) * 2 + (t & 1)) * 1024);
      hdP[ps * 128 + j] = __hip_atomic_load(pq + j, __ATOMIC_RELAXED,
                                            __HIP_MEMORY_SCOPE_AGENT);
    }
    __syncthreads();

    // ---- D: x_h partials (d, kq<8), hist from LDS ----
    {
      float a0 = 0.f, a1 = 0.f, a2 = 0.f, a3 = 0.f;
#pragma unroll
      for (int i = 0; i < 16; ++i) {
        int kp = kqD * 16 + i;
        uint32 w = histL[kp * 128 + dD];
        uint4 h4 = *(const uint4*)&hdP[kp * 4];
        a0 = fdot2(h4.x, w, a0); a1 = fdot2(h4.y, w, a1);
        a2 = fdot2(h4.z, w, a2); a3 = fdot2(h4.w, w, a3);
      }
      scratch[(kqD * 4 + 0) * 128 + dD] = a0;
      scratch[(kqD * 4 + 1) * 128 + dD] = a1;
      scratch[(kqD * 4 + 2) * 128 + dD] = a2;
      scratch[(kqD * 4 + 3) * 128 + dD] = a3;
    }
    __syncthreads();

    // ---- E: xh sum, alpha sum, x_c pack; gamma_x(t+1)+m(t+1) commit ----
    if (tid < 512) {
      xh = hb_s[dA];
#pragma unroll
      for (int kq = 0; kq < 8; ++kq) xh += scratch[(kq * 4 + rA) * 128 + dA];
      av = wcb_s[dA];
#pragma unroll
      for (int kq = 0; kq < 4; ++kq) av += scratch[4096 + (kq * 4 + rA) * 128 + dA];
      float xc = mv * xv + (1.f - mv) * xh;
      float xco = __shfl_down(xc, 1);
      if (!(dA & 1)) xcP[(dA >> 1) * 4 + rA] = packf16(xc, xco);
      float gx = __expf(-fmaxf(fmaf(dvn, txw_s[dA], txb_s[dA]), 0.f));
      float gxo = __shfl_down(gx, 1);
      float dvo = __shfl_down(dvn, 1);
      float mvo = __shfl_down(mvn, 1);
      if (!(dA & 1)) {
        gxmP[(dA >> 1) * 4 + rA] = packf16(gx, gxo);
        gxmP[(64 + (dA >> 1)) * 4 + rA] = packf16(mvn, mvo);
        drP[(dA >> 1) * 4 + rA] = packf16(dvn, dvo);
      }
    }
    __syncthreads();

    // ---- F: z (wf from LDS), c_h, c_c, out (own row), pack [c_c|m] ----
    if (tid < 512) {
      float z = fb_s[dA];
#pragma unroll 16
      for (int kp = 0; kp < 64; ++kp)
        z = fdot2(xcP[kp * 4 + rA], wfL[kp * 128 + dA], z);
      float ch = av * z + (1.f - av) * xh;
      float cc = mv * xv + (1.f - mv) * ch;
      if (rA == sh) outp[base + (size_t)rA * LD + dA] = cc;
      float cco = __shfl_down(cc, 1);
      float mmo = __shfl_down(mv, 1);
      if (!(dA & 1)) {
        cmP[(dA >> 1) * 4 + rA] = packf16(cc, cco);
        cmP[(64 + (dA >> 1)) * 4 + rA] = packf16(mv, mmo);
      }
    }
    __syncthreads();

    // ---- H: gate partials (reg weights) + gamma(t+1) partials ----
    {
      float a[4][2] = {};
#pragma unroll
      for (int i = 0; i < 16; ++i) {
        int kp = kqH * 16 + i;
        uint4 c4 = *(const uint4*)&cmP[kp * 4];
        uint4 h4 = *(const uint4*)&hdP[kp * 4];
        a[0][0] = fdot2(c4.x, wv_[i].x, a[0][0]); a[0][0] = fdot2(h4.x, wh_[i].x, a[0][0]);
        a[0][1] = fdot2(c4.x, wv_[i].y, a[0][1]); a[0][1] = fdot2(h4.x, wh_[i].y, a[0][1]);
        a[1][0] = fdot2(c4.y, wv_[i].x, a[1][0]); a[1][0] = fdot2(h4.y, wh_[i].x, a[1][0]);
        a[1][1] = fdot2(c4.y, wv_[i].y, a[1][1]); a[1][1] = fdot2(h4.y, wh_[i].y, a[1][1]);
        a[2][0] = fdot2(c4.z, wv_[i].x, a[2][0]); a[2][0] = fdot2(h4.z, wh_[i].x, a[2][0]);
        a[2][1] = fdot2(c4.z, wv_[i].y, a[2][1]); a[2][1] = fdot2(h4.z, wh_[i].y, a[2][1]);
        a[3][0] = fdot2(c4.w, wv_[i].x, a[3][0]); a[3][0] = fdot2(h4.w, wh_[i].x, a[3][0]);
        a[3][1] = fdot2(c4.w, wv_[i].y, a[3][1]); a[3][1] = fdot2(h4.w, wh_[i].y, a[3][1]);
      }
#pragma unroll
      for (int r = 0; r < 4; ++r) {
        scratch[(kqH * 16 + r * 4 + 2 * qhH) * 64 + jjH] = a[r][0];
        scratch[(kqH * 16 + r * 4 + 2 * qhH + 1) * 64 + jjH] = a[r][1];
      }
      float gp = 0.f;
#pragma unroll
      for (int i = 0; i < 16; ++i)
        gp = fdot2(drP[(kslG * 16 + i) * 4 + rG], twr[i], gp);
      scratch[8192 + (kslG * 4 + rG) * 64 + jjG] = gp;
    }
    __syncthreads();

    // ---- I: gates reduce + LSTM; gamma(t+1) finalize; prefetch t+2 ----
    if (tid < 512) {
      xv = xvn; mv = mvn;
      int t2 = (t + 2) & 255;
      size_t g2 = b0 * LD + (size_t)t2 * 128 + (size_t)rA * LD + dA;
      xvn = values[g2]; mvn = masks[g2]; dvn = deltas[g2];
    }
    if (tid < 256) {
      int jj = tid & 63, r = tid >> 6;
      float g0 = bg_s[0 * 64 + jj], g1 = bg_s[1 * 64 + jj];
      float g2 = bg_s[2 * 64 + jj], g3 = bg_s[3 * 64 + jj];
#pragma unroll
      for (int kq = 0; kq < 8; ++kq) {
        int bx = (kq * 16 + r * 4) * 64 + jj;
        g0 += scratch[bx]; g1 += scratch[bx + 64];
        g2 += scratch[bx + 128]; g3 += scratch[bx + 192];
      }
      float ig = 1.f / (1.f + __expf(-g0));
      float fg = 1.f / (1.f + __expf(-g1));
      float gg = tanhf(g2);
      float og = 1.f / (1.f + __expf(-g3));
      float c = fg * cst[r][jj] + ig * gg;
      cst[r][jj] = c;
      hf[r][jj] = og * tanhf(c);
      float s = tdhb_s[jj];
#pragma unroll
      for (int ks = 0; ks < 4; ++ks) s += scratch[8192 + (ks * 4 + r) * 64 + jj];
      gbufF[r * 64 + jj] = __expf(-fmaxf(s, 0.f));
    }
    __syncthreads();
  }
}

// ================= K3a: loss from outp (c_c), per-t blocks ==================
__global__ void rits_fin1(const float* __restrict__ values,
                          const float* __restrict__ evalm,
                          const float* __restrict__ outp,
                          char* __restrict__ wsb) {
  const int t = blockIdx.x, tid = threadIdx.x;
  __shared__ float red[256];
  int d = tid & 127, g = tid >> 7;
  float s = 0.f;
  for (int b = g; b < 256; b += 2) {
    size_t ix = (size_t)b * LD + (size_t)t * 128 + d;
    s += fabsf(outp[ix] - values[ix]) * evalm[ix];
  }
  red[tid] = s;
  __syncthreads();
  for (int o = 128; o > 0; o >>= 1) {
    if (tid < o) red[tid] += red[tid + o];
    __syncthreads();
  }
  if (tid == 0)
    atomicAdd((float*)(wsb + OFF_LOSS),
              red[0] / ((const float*)(wsb + OFF_DEN))[t]);
}

// ========================== K3b: loss scalar ================================
__global__ void rits_fin2(const char* __restrict__ wsb, float* __restrict__ outp) {
  if (threadIdx.x == 0 && blockIdx.x == 0)
    outp[(size_t)Bn * LD] = *((const float*)(wsb + OFF_LOSS));
}

// ============================== launcher ====================================
extern "C" void kernel_launch(void* const* d_in, const int* in_sizes, int n_in,
                              void* d_out, int out_size, void* d_ws,
                              size_t ws_size, hipStream_t stream) {
  const float* values = (const float*)d_in[0];
  const float* masks  = (const float*)d_in[1];
  const float* deltas = (const float*)d_in[2];
  const float* evalm  = (const float*)d_in[3];
  const float* td_h_W = (const float*)d_in[4];
  const float* td_h_b = (const float*)d_in[5];
  const float* td_x_w = (const float*)d_in[6];
  const float* td_x_b = (const float*)d_in[7];
  const float* hist_W = (const float*)d_in[8];
  const float* hist_b = (const float*)d_in[9];
  const float* feat_W = (const float*)d_in[10];
  const float* feat_b = (const float*)d_in[11];
  const float* wc_W   = (const float*)d_in[12];
  const float* wc_b   = (const float*)d_in[13];
  const float* W_ih   = (const float*)d_in[14];
  const float* W_hh   = (const float*)d_in[15];
  const float* b_ih   = (const float*)d_in[16];
  const float* b_hh   = (const float*)d_in[17];
  char* wsb = (char*)d_ws;
  float* outp = (float*)d_out;

  hipLaunchKernelGGL(rits_prep, dim3(1509), dim3(256), 0, stream, td_h_W,
                     hist_W, feat_W, wc_W, W_ih, W_hh, b_ih, b_hh, evalm, wsb);
  hipLaunchKernelGGL(rits_rec, dim3(256), dim3(1024), 0, stream, values, masks,
                     deltas, td_h_b, td_x_w, td_x_b, hist_b, feat_b,
                     wc_b, wsb, outp);
  hipLaunchKernelGGL(rits_fin1, dim3(256), dim3(256), 0, stream, values, evalm,
                     outp, wsb);
  hipLaunchKernelGGL(rits_fin2, dim3(1), dim3(64), 0, stream, wsb, outp);
}